// Round 2
// baseline (437.177 us; speedup 1.0000x reference)
//
#include <hip/hip_runtime.h>
#include <hip/hip_cooperative_groups.h>

namespace cg = cooperative_groups;

#define NN   2048
#define F0D  128
#define HIDD 64
#define OUTD 16
#define KDEG 10

// ws float layout:
//   [0]    buf0 (2048)   Krylov vectors p_j, 3-buffer rotation
//   [2048] buf1 (2048)
//   [4096] buf2 (2048)
//   [6144] w    (2048)   accumulated weight vector sum_j c_j p_j (j<K)
//   [8192] Hg   (512)    pooled hidden (B=8 x HID=64)

__global__ __launch_bounds__(256, 1) void k_fused(
    const float* __restrict__ X, const float* __restrict__ L,
    const float* __restrict__ W1, const float* __restrict__ b1,
    const float* __restrict__ W2, const float* __restrict__ b2,
    const float* __restrict__ theta, float* __restrict__ out,
    float* __restrict__ ws)
{
    cg::grid_group grid = cg::this_grid();

    __shared__ float cS[16];
    __shared__ __align__(16) float W1t[64][132];  // W1 transposed, padded stride
    __shared__ float redm[16][65];
    __shared__ __align__(16) float part[4][64];

    float* bufs[3] = {ws, ws + 2048, ws + 4096};
    float* w  = ws + 6144;
    float* Hg = ws + 8192;

    const int bid = blockIdx.x;   // 0..255 (one block per CU)
    const int t   = threadIdx.x;  // 0..255

    // ---- init: zero state, buf0 = ones, monomial coeffs c_j in LDS ----
    int gt = bid * 256 + t;
    if (gt < 8704) ws[gt] = (gt < 2048) ? 1.0f : 0.0f;
    if (t < 16) {
        float cj = 0.f;
        if (t <= KDEG) {
            const float C10[11] = {1,10,45,120,210,252,210,120,45,10,1};
            for (int i = 0; i <= t; ++i) {
                int n = KDEG - i, r = t - i;
                long long cm = 1;
                for (int s = 1; s <= r; ++s) cm = cm * (n - r + s) / s;  // exact
                float term = theta[i] * C10[i] * (float)cm;
                if ((t - i) & 1) term = -term;
                cj += term;
            }
        }
        cS[t] = cj;
    }
    // preload W1^T into LDS (used only in head phase, after many grid syncs)
    for (int i = t; i < F0D * HIDD; i += 256)
        W1t[i & 63][i >> 6] = W1[i];

    grid.sync();

    // ---- Krylov chain: p_j = L^T p_{j-1};  w += c_{j-1} * p_{j-1} ----
    const int ub      = bid & 31;          // u-tile (64 u each)
    const int vchunk  = bid >> 5;          // 0..7 (256 v each)
    const int ugrp    = t & 15;            // 16 float4 columns
    const int wv      = t >> 6;            // wave 0..3
    const int lane    = t & 63;
    const int vstream = wv * 4 + ((t >> 4) & 3);  // 0..15
    const int col     = ub * 16 + ugrp;    // float4 column index
    const int v0      = vchunk * 256;
    const float4* Lp  = (const float4*)L;

    for (int j = 1; j <= KDEG; ++j) {
        const float* x = bufs[(j - 1) % 3];
        float* y = bufs[j % 3];
        float* z = bufs[(j + 1) % 3];           // stale buffer: pre-zero for j+1
        if (t < 8) z[bid * 8 + t] = 0.f;
        if (vchunk == 1 && t < 64) {
            int u = ub * 64 + t;
            w[u] += cS[j - 1] * x[u];
        }
        float4 acc = make_float4(0.f, 0.f, 0.f, 0.f);
        #pragma unroll
        for (int it = 0; it < 16; ++it) {
            int v = v0 + vstream + 16 * it;
            float xv = x[v];
            float4 lv = Lp[(size_t)v * (NN / 4) + col];
            acc.x += lv.x * xv; acc.y += lv.y * xv;
            acc.z += lv.z * xv; acc.w += lv.w * xv;
        }
        // combine the wave's 4 v-streams (lanes differ in bits 4..5)
        acc.x += __shfl_xor(acc.x, 16); acc.y += __shfl_xor(acc.y, 16);
        acc.z += __shfl_xor(acc.z, 16); acc.w += __shfl_xor(acc.w, 16);
        acc.x += __shfl_xor(acc.x, 32); acc.y += __shfl_xor(acc.y, 32);
        acc.z += __shfl_xor(acc.z, 32); acc.w += __shfl_xor(acc.w, 32);
        if (lane < 16) *(float4*)&part[wv][ugrp * 4] = acc;
        __syncthreads();
        if (t < 64) {
            float s = part[0][t] + part[1][t] + part[2][t] + part[3][t];
            atomicAdd(&y[ub * 64 + t], s);     // 8 partials per address
        }
        grid.sync();
    }

    // ---- head: Hg[b,h] = (1/N) sum_v weff[v] * relu(X[b,v,:]W1 + b1)[h] ----
    {
        const float* pK = bufs[KDEG % 3];      // p_K
        const int b   = bid >> 5;              // batch 0..7
        const int vch = bid & 31;              // 32 chunks x 64 v
        const int hg  = t & 15;
        const int vg  = t >> 4;
        const int vbase = vch * 64 + vg * 4;
        const float* Xb = X + ((size_t)b * NN + vbase) * F0D;
        float acc[4][4] = {};
        for (int f = 0; f < F0D; f += 4) {
            float4 xr[4];
            #pragma unroll
            for (int i = 0; i < 4; ++i)
                xr[i] = *(const float4*)(Xb + (size_t)i * F0D + f);
            #pragma unroll
            for (int jj = 0; jj < 4; ++jj) {
                float4 wr = *(const float4*)(&W1t[hg + 16 * jj][f]);
                #pragma unroll
                for (int i = 0; i < 4; ++i)
                    acc[i][jj] += xr[i].x * wr.x + xr[i].y * wr.y
                                + xr[i].z * wr.z + xr[i].w * wr.w;
            }
        }
        float cK = cS[KDEG];
        float hsum[4] = {0.f, 0.f, 0.f, 0.f};
        #pragma unroll
        for (int i = 0; i < 4; ++i) {
            int v = vbase + i;
            float weff = w[v] + cK * pK[v];
            #pragma unroll
            for (int jj = 0; jj < 4; ++jj) {
                float r = acc[i][jj] + b1[hg + 16 * jj];
                r = r > 0.f ? r : 0.f;
                hsum[jj] += r * weff;
            }
        }
        #pragma unroll
        for (int jj = 0; jj < 4; ++jj) redm[vg][hg + 16 * jj] = hsum[jj];
        __syncthreads();
        if (t < 64) {
            float s = 0.f;
            #pragma unroll
            for (int i = 0; i < 16; ++i) s += redm[i][t];
            atomicAdd(&Hg[b * 64 + t], s * (1.0f / (float)NN));
        }
    }
    grid.sync();

    // ---- output layer: logits = Hg @ W2 + b2 ----
    if (bid == 0 && t < 128) {
        int o = t & 15, b = t >> 4;
        float acc = b2[o];
        #pragma unroll
        for (int h = 0; h < HIDD; ++h) acc += Hg[b * 64 + h] * W2[h * 16 + o];
        out[b * 16 + o] = acc;
    }
}

extern "C" void kernel_launch(void* const* d_in, const int* in_sizes, int n_in,
                              void* d_out, int out_size, void* d_ws, size_t ws_size,
                              hipStream_t stream) {
    const float* X     = (const float*)d_in[0];
    const float* L     = (const float*)d_in[1];
    const float* W1    = (const float*)d_in[2];
    const float* b1    = (const float*)d_in[3];
    const float* W2    = (const float*)d_in[4];
    const float* b2    = (const float*)d_in[5];
    const float* theta = (const float*)d_in[6];
    // d_in[7] = dp = 0 -> dropout is identity; ignored.
    float* outp = (float*)d_out;
    float* ws   = (float*)d_ws;

    void* args[] = {(void*)&X, (void*)&L, (void*)&W1, (void*)&b1,
                    (void*)&W2, (void*)&b2, (void*)&theta, (void*)&outp,
                    (void*)&ws};
    hipLaunchCooperativeKernel((void*)k_fused, dim3(256), dim3(256),
                               args, 0, stream);
}

// Round 3
// 186.824 us; speedup vs baseline: 2.3400x; 2.3400x over previous
//
#include <hip/hip_runtime.h>

#define NN   2048
#define F0D  128
#define HIDD 64
#define OUTD 16
#define KDEG 10

// ws float layout:
//   [0 .. 22527]      p[j] = (L^T)^j * 1, j = 0..10, each 2048 floats
//   [22528 .. 23039]  Hg (B=8 x HID=64)
//   [23040 .. 23295]  barrier slots (256 ints; 0xAA poison is negative)
#define P_OFF   0
#define HG_OFF  22528
#define SL_OFF  23040

__device__ __forceinline__ void gbar(int* slots, int token) {
    __builtin_amdgcn_s_waitcnt(0);          // drain this wave's outstanding mem ops
    __syncthreads();                         // whole block done + drained
    if (threadIdx.x == 0)
        __hip_atomic_store(&slots[blockIdx.x], token,
                           __ATOMIC_RELAXED, __HIP_MEMORY_SCOPE_AGENT);
    // 256 threads each poll one block's slot (grid == blockDim == 256)
    while (__hip_atomic_load(&slots[threadIdx.x],
                             __ATOMIC_RELAXED, __HIP_MEMORY_SCOPE_AGENT) < token)
        __builtin_amdgcn_s_sleep(1);
    __syncthreads();
}

__global__ __launch_bounds__(256, 1) void k_fused(
    const float* __restrict__ X, const float* __restrict__ L,
    const float* __restrict__ W1, const float* __restrict__ b1,
    const float* __restrict__ W2, const float* __restrict__ b2,
    const float* __restrict__ theta, float* __restrict__ out,
    float* __restrict__ ws)
{
    __shared__ float cS[16];
    __shared__ __align__(16) float W1t[64][132];   // W1^T, padded stride
    __shared__ float redm[16][65];
    __shared__ __align__(16) float part[4][64];
    __shared__ float xs[256];

    float* pbuf = ws + P_OFF;                 // 11 x 2048
    float* Hg   = ws + HG_OFF;
    int*   slots = (int*)(ws + SL_OFF);

    const int bid = blockIdx.x;               // 0..255, one block per CU
    const int t   = threadIdx.x;              // 0..255

    // ---- init: p0 = 1, p1..p10 = 0, Hg = 0 (all via IC-coherent stores) ----
    int gt = bid * 256 + t;
    if (gt < 23040) {
        float v = (gt < 2048) ? 1.0f : 0.0f;
        __hip_atomic_store(&ws[gt], v, __ATOMIC_RELAXED, __HIP_MEMORY_SCOPE_AGENT);
    }
    if (t < 16) {
        float cj = 0.f;
        if (t <= KDEG) {
            const float C10[11] = {1,10,45,120,210,252,210,120,45,10,1};
            for (int i = 0; i <= t; ++i) {
                int n = KDEG - i, r = t - i;
                long long cm = 1;
                for (int s = 1; s <= r; ++s) cm = cm * (n - r + s) / s;  // exact
                float term = theta[i] * C10[i] * (float)cm;
                if ((t - i) & 1) term = -term;
                cj += term;
            }
        }
        cS[t] = cj;
    }
    for (int i = t; i < F0D * HIDD; i += 256)
        W1t[i & 63][i >> 6] = W1[i];

    gbar(slots, 1);

    // ---- Krylov chain: p_j = L^T p_{j-1} ----
    const int ub      = bid & 31;             // u-tile (64 u each)
    const int vchunk  = bid >> 5;             // 0..7 (256 v each)
    const int ugrp    = t & 15;               // 16 float4 columns
    const int wv      = t >> 6;               // wave 0..3
    const int lane    = t & 63;
    const int vstream = wv * 4 + ((t >> 4) & 3);   // 0..15
    const int col     = ub * 16 + ugrp;       // float4 column index
    const int v0      = vchunk * 256;
    const float4* Lp  = (const float4*)L;

    for (int j = 1; j <= KDEG; ++j) {
        const float* x = pbuf + (j - 1) * NN;
        float*       y = pbuf + j * NN;
        // stage the 256 x-values this block needs into LDS (IC-coherent loads)
        xs[t] = __hip_atomic_load(&x[v0 + t], __ATOMIC_RELAXED,
                                  __HIP_MEMORY_SCOPE_AGENT);
        __syncthreads();
        float4 acc = make_float4(0.f, 0.f, 0.f, 0.f);
        #pragma unroll
        for (int it = 0; it < 16; ++it) {
            int vl = vstream + 16 * it;
            float xv = xs[vl];
            float4 lv = Lp[(size_t)(v0 + vl) * (NN / 4) + col];
            acc.x += lv.x * xv; acc.y += lv.y * xv;
            acc.z += lv.z * xv; acc.w += lv.w * xv;
        }
        acc.x += __shfl_xor(acc.x, 16); acc.y += __shfl_xor(acc.y, 16);
        acc.z += __shfl_xor(acc.z, 16); acc.w += __shfl_xor(acc.w, 16);
        acc.x += __shfl_xor(acc.x, 32); acc.y += __shfl_xor(acc.y, 32);
        acc.z += __shfl_xor(acc.z, 32); acc.w += __shfl_xor(acc.w, 32);
        if (lane < 16) *(float4*)&part[wv][ugrp * 4] = acc;
        __syncthreads();
        if (t < 64) {
            float s = part[0][t] + part[1][t] + part[2][t] + part[3][t];
            atomicAdd(&y[ub * 64 + t], s);    // 8 partials per address, via IC
        }
        gbar(slots, 1 + j);
    }

    // ---- head: Hg[b,h] = (1/N) sum_v weff[v] * relu(X[b,v,:]W1 + b1)[h] ----
    {
        const int b   = bid >> 5;             // batch 0..7
        const int vch = bid & 31;             // 32 chunks x 64 v
        const int hg  = t & 15;
        const int vg  = t >> 4;
        const int vbase = vch * 64 + vg * 4;
        const float* Xb = X + ((size_t)b * NN + vbase) * F0D;
        float acc[4][4] = {};
        for (int f = 0; f < F0D; f += 4) {
            float4 xr[4];
            #pragma unroll
            for (int i = 0; i < 4; ++i)
                xr[i] = *(const float4*)(Xb + (size_t)i * F0D + f);
            #pragma unroll
            for (int jj = 0; jj < 4; ++jj) {
                float4 wr = *(const float4*)(&W1t[hg + 16 * jj][f]);
                #pragma unroll
                for (int i = 0; i < 4; ++i)
                    acc[i][jj] += xr[i].x * wr.x + xr[i].y * wr.y
                                + xr[i].z * wr.z + xr[i].w * wr.w;
            }
        }
        float hsum[4] = {0.f, 0.f, 0.f, 0.f};
        #pragma unroll
        for (int i = 0; i < 4; ++i) {
            int v = vbase + i;
            float weff = 0.f;
            #pragma unroll
            for (int jd = 0; jd <= KDEG; ++jd)
                weff += cS[jd] * __hip_atomic_load(&pbuf[jd * NN + v],
                        __ATOMIC_RELAXED, __HIP_MEMORY_SCOPE_AGENT);
            #pragma unroll
            for (int jj = 0; jj < 4; ++jj) {
                float r = acc[i][jj] + b1[hg + 16 * jj];
                r = r > 0.f ? r : 0.f;
                hsum[jj] += r * weff;
            }
        }
        #pragma unroll
        for (int jj = 0; jj < 4; ++jj) redm[vg][hg + 16 * jj] = hsum[jj];
        __syncthreads();
        if (t < 64) {
            float s = 0.f;
            #pragma unroll
            for (int i = 0; i < 16; ++i) s += redm[i][t];
            atomicAdd(&Hg[b * 64 + t], s * (1.0f / (float)NN));
        }
    }
    gbar(slots, KDEG + 2);

    // ---- output layer: logits = Hg @ W2 + b2 (block 0 only) ----
    if (bid == 0 && t < 128) {
        int o = t & 15, b = t >> 4;
        float acc = b2[o];
        #pragma unroll
        for (int h = 0; h < HIDD; ++h)
            acc += __hip_atomic_load(&Hg[b * 64 + h], __ATOMIC_RELAXED,
                                     __HIP_MEMORY_SCOPE_AGENT) * W2[h * 16 + o];
        out[b * 16 + o] = acc;
    }
}

extern "C" void kernel_launch(void* const* d_in, const int* in_sizes, int n_in,
                              void* d_out, int out_size, void* d_ws, size_t ws_size,
                              hipStream_t stream) {
    const float* X     = (const float*)d_in[0];
    const float* L     = (const float*)d_in[1];
    const float* W1    = (const float*)d_in[2];
    const float* b1    = (const float*)d_in[3];
    const float* W2    = (const float*)d_in[4];
    const float* b2    = (const float*)d_in[5];
    const float* theta = (const float*)d_in[6];
    // d_in[7] = dp = 0 -> dropout identity; ignored.
    float* outp = (float*)d_out;
    float* ws   = (float*)d_ws;

    void* args[] = {(void*)&X, (void*)&L, (void*)&W1, (void*)&b1,
                    (void*)&W2, (void*)&b2, (void*)&theta, (void*)&outp,
                    (void*)&ws};
    hipLaunchCooperativeKernel((void*)k_fused, dim3(256), dim3(256),
                               args, 0, stream);
}